// Round 1
// baseline (3092.514 us; speedup 1.0000x reference)
//
#include <hip/hip_runtime.h>

#define IN_F 128
#define OUT_F 128
#define TILE_E 64
#define XS_STRIDE 130   // pad 128 -> 130: column reads drop 16-way->4-way bank conflict

// ---------------- Kernel 1: rel_w[r,i,o] = sum_b coeff[r,b] * weight[b,i,o] ----
__global__ void k_relw(const float* __restrict__ w, const float* __restrict__ c,
                       float* __restrict__ rw, int R, int B) {
  int idx = blockIdx.x * blockDim.x + threadIdx.x;
  if (idx >= R * IN_F * OUT_F) return;
  int r = idx >> 14;               // / 16384
  int io = idx & (IN_F * OUT_F - 1);
  float acc = 0.f;
  for (int b = 0; b < B; ++b) acc = fmaf(c[r * B + b], w[b * IN_F * OUT_F + io], acc);
  rw[idx] = acc;
}

// ---------------- Kernel 2: relation histogram + in-degree --------------------
__global__ void k_hist_deg(const int* __restrict__ etype, const int* __restrict__ tgt,
                           int E, int R, int* __restrict__ hist, float* __restrict__ deg) {
  __shared__ int lh[64];
  int tid = threadIdx.x;
  if (tid < R) lh[tid] = 0;
  __syncthreads();
  int e = blockIdx.x * blockDim.x + tid;
  if (e < E) {
    atomicAdd(&lh[etype[e]], 1);
    atomicAdd(&deg[tgt[e]], 1.0f);
  }
  __syncthreads();
  if (tid < R && lh[tid]) atomicAdd(&hist[tid], lh[tid]);
}

// ---------------- Kernel 3: tiny scan over R bins -----------------------------
__global__ void k_scan(const int* __restrict__ hist, int* __restrict__ offs,
                       int* __restrict__ toffs, int R) {
  if (threadIdx.x == 0) {
    int s = 0, t = 0;
    for (int r = 0; r < R; ++r) {
      offs[r] = s; toffs[r] = t;
      s += hist[r];
      t += (hist[r] + TILE_E - 1) / TILE_E;
    }
    offs[R] = s; toffs[R] = t;
  }
}

// ---------------- Kernel 4: counting-sort scatter of edge ids -----------------
__global__ void k_scatter(const int* __restrict__ etype, int E, int R,
                          const int* __restrict__ offs, int* __restrict__ cursor,
                          int* __restrict__ perm) {
  __shared__ int lh[64], lbase[64], lcur[64];
  int tid = threadIdx.x;
  if (tid < R) { lh[tid] = 0; lcur[tid] = 0; }
  __syncthreads();
  int e = blockIdx.x * blockDim.x + tid;
  int t = -1;
  if (e < E) { t = etype[e]; atomicAdd(&lh[t], 1); }
  __syncthreads();
  if (tid < R) lbase[tid] = lh[tid] ? atomicAdd(&cursor[tid], lh[tid]) : 0;
  __syncthreads();
  if (e < E) {
    int loc = atomicAdd(&lcur[t], 1);
    perm[offs[t] + lbase[t] + loc] = e;
  }
}

// ---------------- Kernel 5: per-relation-tile message GEMM + scatter-add ------
__global__ __launch_bounds__(256) void k_msg(
    const float* __restrict__ x, const int* __restrict__ src,
    const int* __restrict__ tgt, const int* __restrict__ perm,
    const int* __restrict__ offs, const int* __restrict__ toffs,
    const float* __restrict__ rw, float* __restrict__ out, int R) {
  __shared__ float xs[TILE_E * XS_STRIDE];   // 33,280 B
  __shared__ float ws[16 * OUT_F];           //  8,192 B
  __shared__ int ssrc[TILE_E], stgt[TILE_E];
  __shared__ int sinfo[2];
  int tid = threadIdx.x;
  int bid = blockIdx.x;
  if (tid == 0) {
    int r = -1;
    if (bid < toffs[R]) {
      r = 0;
      while (!(bid >= toffs[r] && bid < toffs[r + 1])) ++r;
    }
    sinfo[0] = r;
    sinfo[1] = (r >= 0) ? (offs[r] + (bid - toffs[r]) * TILE_E) : 0;
  }
  __syncthreads();
  int r = sinfo[0];
  if (r < 0) return;
  int ebase = sinfo[1];
  int cnt = min(TILE_E, offs[r + 1] - ebase);

  if (tid < TILE_E) {
    if (tid < cnt) {
      int e = perm[ebase + tid];
      ssrc[tid] = src[e];
      stgt[tid] = tgt[e];
    } else {
      ssrc[tid] = -1;
      stgt[tid] = -1;
    }
  }
  __syncthreads();

  // stage x rows (64 x 128 fp32) into LDS, padded stride
  const float4* x4 = (const float4*)x;
  #pragma unroll
  for (int i = 0; i < 8; ++i) {
    int idx = i * 256 + tid;       // float4 slot 0..2047
    int e = idx >> 5;
    int c = idx & 31;
    float4 v = make_float4(0.f, 0.f, 0.f, 0.f);
    int s = ssrc[e];
    if (s >= 0) v = x4[(size_t)s * 32 + c];
    float* p = &xs[e * XS_STRIDE + c * 4];
    p[0] = v.x; p[1] = v.y; p[2] = v.z; p[3] = v.w;
  }

  float acc[4][8];
  #pragma unroll
  for (int a = 0; a < 4; ++a)
    #pragma unroll
    for (int b = 0; b < 8; ++b) acc[a][b] = 0.f;

  int te = tid >> 4, tf = tid & 15;
  const float4* wg4 = (const float4*)(rw + (size_t)r * IN_F * OUT_F);
  float4* ws4 = (float4*)ws;

  for (int k0 = 0; k0 < IN_F; k0 += 16) {
    __syncthreads();
    #pragma unroll
    for (int i = 0; i < 2; ++i) {
      int fi = tid * 2 + i;        // 0..511
      int kk = fi >> 5, c = fi & 31;
      ws4[fi] = wg4[(k0 + kk) * 32 + c];
    }
    __syncthreads();
    #pragma unroll
    for (int kk = 0; kk < 16; ++kk) {
      float4 w0 = ws4[kk * 32 + tf * 2];
      float4 w1 = ws4[kk * 32 + tf * 2 + 1];
      #pragma unroll
      for (int rr = 0; rr < 4; ++rr) {
        float a = xs[(te * 4 + rr) * XS_STRIDE + k0 + kk];
        acc[rr][0] = fmaf(a, w0.x, acc[rr][0]);
        acc[rr][1] = fmaf(a, w0.y, acc[rr][1]);
        acc[rr][2] = fmaf(a, w0.z, acc[rr][2]);
        acc[rr][3] = fmaf(a, w0.w, acc[rr][3]);
        acc[rr][4] = fmaf(a, w1.x, acc[rr][4]);
        acc[rr][5] = fmaf(a, w1.y, acc[rr][5]);
        acc[rr][6] = fmaf(a, w1.z, acc[rr][6]);
        acc[rr][7] = fmaf(a, w1.w, acc[rr][7]);
      }
    }
  }

  #pragma unroll
  for (int rr = 0; rr < 4; ++rr) {
    int row = te * 4 + rr;
    if (row < cnt) {
      int t = stgt[row];
      float* op = out + (size_t)t * OUT_F + tf * 8;
      #pragma unroll
      for (int i = 0; i < 8; ++i) atomicAdd(&op[i], acc[rr][i]);
    }
  }
}

// ------------- Kernel 6: self-loop GEMM + deg-normalize + bias ----------------
__global__ __launch_bounds__(256) void k_self(
    const float* __restrict__ x, const float* __restrict__ sw,
    const float* __restrict__ bias, const float* __restrict__ deg,
    float* __restrict__ out, int N) {
  __shared__ float xs[TILE_E * XS_STRIDE];
  __shared__ float ws[16 * OUT_F];
  __shared__ float sdeg[TILE_E];
  int tid = threadIdx.x;
  int base = blockIdx.x * TILE_E;
  int cnt = min(TILE_E, N - base);
  if (cnt <= 0) return;

  if (tid < TILE_E) {
    int n = base + tid;
    float d = (n < N) ? deg[n] : 1.f;
    sdeg[tid] = 1.f / fmaxf(d, 1.f);
  }
  const float4* x4 = (const float4*)x;
  #pragma unroll
  for (int i = 0; i < 8; ++i) {
    int idx = i * 256 + tid;
    int e = idx >> 5;
    int c = idx & 31;
    int n = base + e;
    float4 v = make_float4(0.f, 0.f, 0.f, 0.f);
    if (n < N) v = x4[(size_t)n * 32 + c];
    float* p = &xs[e * XS_STRIDE + c * 4];
    p[0] = v.x; p[1] = v.y; p[2] = v.z; p[3] = v.w;
  }

  float acc[4][8];
  #pragma unroll
  for (int a = 0; a < 4; ++a)
    #pragma unroll
    for (int b = 0; b < 8; ++b) acc[a][b] = 0.f;

  int te = tid >> 4, tf = tid & 15;
  const float4* wg4 = (const float4*)sw;
  float4* ws4 = (float4*)ws;

  for (int k0 = 0; k0 < IN_F; k0 += 16) {
    __syncthreads();
    #pragma unroll
    for (int i = 0; i < 2; ++i) {
      int fi = tid * 2 + i;
      int kk = fi >> 5, c = fi & 31;
      ws4[fi] = wg4[(k0 + kk) * 32 + c];
    }
    __syncthreads();
    #pragma unroll
    for (int kk = 0; kk < 16; ++kk) {
      float4 w0 = ws4[kk * 32 + tf * 2];
      float4 w1 = ws4[kk * 32 + tf * 2 + 1];
      #pragma unroll
      for (int rr = 0; rr < 4; ++rr) {
        float a = xs[(te * 4 + rr) * XS_STRIDE + k0 + kk];
        acc[rr][0] = fmaf(a, w0.x, acc[rr][0]);
        acc[rr][1] = fmaf(a, w0.y, acc[rr][1]);
        acc[rr][2] = fmaf(a, w0.z, acc[rr][2]);
        acc[rr][3] = fmaf(a, w0.w, acc[rr][3]);
        acc[rr][4] = fmaf(a, w1.x, acc[rr][4]);
        acc[rr][5] = fmaf(a, w1.y, acc[rr][5]);
        acc[rr][6] = fmaf(a, w1.z, acc[rr][6]);
        acc[rr][7] = fmaf(a, w1.w, acc[rr][7]);
      }
    }
  }

  #pragma unroll
  for (int rr = 0; rr < 4; ++rr) {
    int row = te * 4 + rr;
    if (row < cnt) {
      int n = base + row;
      float inv = sdeg[row];
      float* op = out + (size_t)n * OUT_F + tf * 8;
      const float* bp = bias + tf * 8;
      #pragma unroll
      for (int i = 0; i < 8; ++i) op[i] = op[i] * inv + acc[rr][i] + bp[i];
    }
  }
}

// ------------------------------- launch ---------------------------------------
extern "C" void kernel_launch(void* const* d_in, const int* in_sizes, int n_in,
                              void* d_out, int out_size, void* d_ws, size_t ws_size,
                              hipStream_t stream) {
  const float* x      = (const float*)d_in[0];
  const int*   ei     = (const int*)d_in[1];   // [2][E] int32
  const int*   etype  = (const int*)d_in[2];   // [E]
  const float* weight = (const float*)d_in[4]; // [B][128][128]
  const float* coeff  = (const float*)d_in[5]; // [R][B]
  const float* selfw  = (const float*)d_in[6]; // [128][128]
  const float* bias   = (const float*)d_in[7]; // [128]

  int N = in_sizes[0] / IN_F;
  int E = in_sizes[2];
  int B = in_sizes[4] / (IN_F * OUT_F);
  int R = in_sizes[5] / B;
  const int* src = ei;
  const int* tgt = ei + E;

  char* ws = (char*)d_ws;
  size_t off = 0;
  float* relw = (float*)(ws + off); off += (size_t)R * IN_F * OUT_F * 4;
  size_t npad = (size_t)((N + 3) & ~3);
  float* deg  = (float*)(ws + off); off += npad * 4;
  int* hist   = (int*)(ws + off);   off += 64 * 4;
  int* cursor = (int*)(ws + off);   off += 64 * 4;
  int* offs   = (int*)(ws + off);   off += 64 * 4;
  int* toffs  = (int*)(ws + off);   off += 64 * 4;
  int* perm   = (int*)(ws + off);   off += (size_t)E * 4;

  // zero: output accumulator + [deg | hist | cursor] (contiguous)
  hipMemsetAsync(d_out, 0, (size_t)out_size * 4, stream);
  hipMemsetAsync(deg, 0, (npad + 128) * 4, stream);

  k_relw<<<(R * IN_F * OUT_F + 255) / 256, 256, 0, stream>>>(weight, coeff, relw, R, B);
  k_hist_deg<<<(E + 255) / 256, 256, 0, stream>>>(etype, tgt, E, R, hist, deg);
  k_scan<<<1, 64, 0, stream>>>(hist, offs, toffs, R);
  k_scatter<<<(E + 255) / 256, 256, 0, stream>>>(etype, E, R, offs, cursor, perm);

  int maxTiles = (E + TILE_E - 1) / TILE_E + R;
  k_msg<<<maxTiles, 256, 0, stream>>>(x, src, tgt, perm, offs, toffs, relw,
                                      (float*)d_out, R);
  k_self<<<(N + TILE_E - 1) / TILE_E, 256, 0, stream>>>(x, selfw, bias, deg,
                                                        (float*)d_out, N);
}

// Round 2
// 826.659 us; speedup vs baseline: 3.7410x; 3.7410x over previous
//
#include <hip/hip_runtime.h>

#define IN_F 128
#define OUT_F 128
#define TILE_E 64
#define XS_STRIDE 132   // mult of 4 -> aligned float4 LDS stores; reads are broadcast

typedef unsigned int uint;
typedef unsigned short ushort;

__device__ inline ushort f2bf(float f) {
  uint u = __float_as_uint(f);
  uint r = (u + 0x7FFFu + ((u >> 16) & 1u)) >> 16;
  return (ushort)r;
}

// ---------------- Kernel 1: rel_w[r,i,o] = sum_b coeff[r,b] * weight[b,i,o] ----
__global__ void k_relw(const float* __restrict__ w, const float* __restrict__ c,
                       float* __restrict__ rw, int R, int B) {
  int idx = blockIdx.x * blockDim.x + threadIdx.x;
  if (idx >= R * IN_F * OUT_F) return;
  int r = idx >> 14;
  int io = idx & (IN_F * OUT_F - 1);
  float acc = 0.f;
  for (int b = 0; b < B; ++b) acc = fmaf(c[r * B + b], w[b * IN_F * OUT_F + io], acc);
  rw[idx] = acc;
}

// ---------------- Kernel 2: relation histogram + int in-degree ----------------
__global__ void k_hist_deg(const int* __restrict__ etype, const int* __restrict__ tgt,
                           int E, int R, int* __restrict__ hist, int* __restrict__ ideg) {
  __shared__ int lh[64];
  int tid = threadIdx.x;
  if (tid < R) lh[tid] = 0;
  __syncthreads();
  int e = blockIdx.x * blockDim.x + tid;
  if (e < E) {
    atomicAdd(&lh[etype[e]], 1);
    atomicAdd(&ideg[tgt[e]], 1);
  }
  __syncthreads();
  if (tid < R && lh[tid]) atomicAdd(&hist[tid], lh[tid]);
}

// ---------------- Kernel 3: tiny scan over R bins -----------------------------
__global__ void k_scan(const int* __restrict__ hist, int* __restrict__ offs,
                       int* __restrict__ toffs, int R) {
  if (threadIdx.x == 0) {
    int s = 0, t = 0;
    for (int r = 0; r < R; ++r) {
      offs[r] = s; toffs[r] = t;
      s += hist[r];
      t += (hist[r] + TILE_E - 1) / TILE_E;
    }
    offs[R] = s; toffs[R] = t;
  }
}

// ---------------- Kernel 4: counting-sort scatter of edge ids by relation -----
__global__ void k_scatter(const int* __restrict__ etype, int E, int R,
                          const int* __restrict__ offs, int* __restrict__ cursor,
                          int* __restrict__ perm) {
  __shared__ int lh[64], lbase[64], lcur[64];
  int tid = threadIdx.x;
  if (tid < R) { lh[tid] = 0; lcur[tid] = 0; }
  __syncthreads();
  int e = blockIdx.x * blockDim.x + tid;
  int t = -1;
  if (e < E) { t = etype[e]; atomicAdd(&lh[t], 1); }
  __syncthreads();
  if (tid < R) lbase[tid] = lh[tid] ? atomicAdd(&cursor[tid], lh[tid]) : 0;
  __syncthreads();
  if (e < E) {
    int loc = atomicAdd(&lcur[t], 1);
    perm[offs[t] + lbase[t] + loc] = e;
  }
}

// ---------------- Kernel 5: exclusive scan of node degrees (single block) -----
__global__ __launch_bounds__(1024) void k_scan_nodes(
    const int* __restrict__ ideg, int* __restrict__ row_off, int N) {
  __shared__ int part[1024];
  int tid = threadIdx.x;
  int chunk = (N + 1023) >> 10;
  int lo = tid * chunk, hi = min(lo + chunk, N);
  int s = 0;
  for (int i = lo; i < hi; ++i) s += ideg[i];
  part[tid] = s;
  __syncthreads();
  for (int d = 1; d < 1024; d <<= 1) {
    int v = (tid >= d) ? part[tid - d] : 0;
    __syncthreads();
    part[tid] += v;
    __syncthreads();
  }
  int pre = (tid > 0) ? part[tid - 1] : 0;
  for (int i = lo; i < hi; ++i) { row_off[i] = pre; pre += ideg[i]; }
  if (tid == 1023) row_off[N] = part[1023];
}

// ---------------- Kernel 6: scatter edge ids into target-CSR ------------------
__global__ void k_scatter_tgt(const int* __restrict__ tgt, int E,
                              const int* __restrict__ row_off,
                              int* __restrict__ cursor, int* __restrict__ csr) {
  int e = blockIdx.x * blockDim.x + threadIdx.x;
  if (e < E) {
    int t = tgt[e];
    int pos = row_off[t] + atomicAdd(&cursor[t], 1);
    csr[pos] = e;
  }
}

// ---------------- Kernel 7: per-relation-tile message GEMM -> bf16 msg --------
__global__ __launch_bounds__(256) void k_msg(
    const float* __restrict__ x, const int* __restrict__ src,
    const int* __restrict__ perm,
    const int* __restrict__ offs, const int* __restrict__ toffs,
    const float* __restrict__ rw, ushort* __restrict__ msg, int R) {
  __shared__ float xs[TILE_E * XS_STRIDE];   // 33,792 B
  __shared__ float ws[16 * OUT_F];           //  8,192 B
  __shared__ int ssrc[TILE_E], sed[TILE_E];
  __shared__ int sinfo[2];
  int tid = threadIdx.x;
  int bid = blockIdx.x;
  if (tid == 0) {
    int r = -1;
    if (bid < toffs[R]) {
      r = 0;
      while (!(bid >= toffs[r] && bid < toffs[r + 1])) ++r;
    }
    sinfo[0] = r;
    sinfo[1] = (r >= 0) ? (offs[r] + (bid - toffs[r]) * TILE_E) : 0;
  }
  __syncthreads();
  int r = sinfo[0];
  if (r < 0) return;
  int ebase = sinfo[1];
  int cnt = min(TILE_E, offs[r + 1] - ebase);

  if (tid < TILE_E) {
    if (tid < cnt) {
      int e = perm[ebase + tid];
      ssrc[tid] = src[e];
      sed[tid] = e;
    } else {
      ssrc[tid] = -1;
      sed[tid] = -1;
    }
  }
  __syncthreads();

  // stage x rows (64 x 128 fp32) into LDS
  const float4* x4 = (const float4*)x;
  #pragma unroll
  for (int i = 0; i < 8; ++i) {
    int idx = i * 256 + tid;       // float4 slot 0..2047
    int e = idx >> 5;
    int c = idx & 31;
    float4 v = make_float4(0.f, 0.f, 0.f, 0.f);
    int s = ssrc[e];
    if (s >= 0) v = x4[(size_t)s * 32 + c];
    *(float4*)(&xs[e * XS_STRIDE + c * 4]) = v;
  }

  float acc[4][8];
  #pragma unroll
  for (int a = 0; a < 4; ++a)
    #pragma unroll
    for (int b = 0; b < 8; ++b) acc[a][b] = 0.f;

  int te = tid >> 4, tf = tid & 15;
  const float4* wg4 = (const float4*)(rw + (size_t)r * IN_F * OUT_F);
  float4* ws4 = (float4*)ws;

  for (int k0 = 0; k0 < IN_F; k0 += 16) {
    __syncthreads();
    #pragma unroll
    for (int i = 0; i < 2; ++i) {
      int fi = i * 256 + tid;      // consecutive lanes -> consecutive float4 (2-way free)
      ws4[fi] = wg4[k0 * 32 + fi];
    }
    __syncthreads();
    #pragma unroll
    for (int kk = 0; kk < 16; ++kk) {
      float4 w0 = ws4[kk * 32 + tf];        // cols tf*4..+3      (2-way, free)
      float4 w1 = ws4[kk * 32 + 16 + tf];   // cols 64+tf*4..+3
      #pragma unroll
      for (int rr = 0; rr < 4; ++rr) {
        float a = xs[(te * 4 + rr) * XS_STRIDE + k0 + kk];  // broadcast
        acc[rr][0] = fmaf(a, w0.x, acc[rr][0]);
        acc[rr][1] = fmaf(a, w0.y, acc[rr][1]);
        acc[rr][2] = fmaf(a, w0.z, acc[rr][2]);
        acc[rr][3] = fmaf(a, w0.w, acc[rr][3]);
        acc[rr][4] = fmaf(a, w1.x, acc[rr][4]);
        acc[rr][5] = fmaf(a, w1.y, acc[rr][5]);
        acc[rr][6] = fmaf(a, w1.z, acc[rr][6]);
        acc[rr][7] = fmaf(a, w1.w, acc[rr][7]);
      }
    }
  }

  // epilogue: bf16-pack, coalesced 8B stores, no atomics
  #pragma unroll
  for (int rr = 0; rr < 4; ++rr) {
    int row = te * 4 + rr;
    if (row < cnt) {
      int e = sed[row];
      uint2 p0, p1;
      p0.x = (uint)f2bf(acc[rr][0]) | ((uint)f2bf(acc[rr][1]) << 16);
      p0.y = (uint)f2bf(acc[rr][2]) | ((uint)f2bf(acc[rr][3]) << 16);
      p1.x = (uint)f2bf(acc[rr][4]) | ((uint)f2bf(acc[rr][5]) << 16);
      p1.y = (uint)f2bf(acc[rr][6]) | ((uint)f2bf(acc[rr][7]) << 16);
      *(uint2*)(msg + (size_t)e * OUT_F + tf * 4) = p0;        // cols tf*4..+3
      *(uint2*)(msg + (size_t)e * OUT_F + 64 + tf * 4) = p1;   // cols 64+tf*4..+3
    }
  }
}

// ------------- Kernel 8: self-loop GEMM + bias (writes full out) --------------
__global__ __launch_bounds__(256) void k_self(
    const float* __restrict__ x, const float* __restrict__ sw,
    const float* __restrict__ bias, float* __restrict__ out, int N) {
  __shared__ float xs[TILE_E * XS_STRIDE];
  __shared__ float ws[16 * OUT_F];
  int tid = threadIdx.x;
  int base = blockIdx.x * TILE_E;
  int cnt = min(TILE_E, N - base);
  if (cnt <= 0) return;

  const float4* x4 = (const float4*)x;
  #pragma unroll
  for (int i = 0; i < 8; ++i) {
    int idx = i * 256 + tid;
    int e = idx >> 5;
    int c = idx & 31;
    int n = base + e;
    float4 v = make_float4(0.f, 0.f, 0.f, 0.f);
    if (n < N) v = x4[(size_t)n * 32 + c];
    *(float4*)(&xs[e * XS_STRIDE + c * 4]) = v;
  }

  float acc[4][8];
  #pragma unroll
  for (int a = 0; a < 4; ++a)
    #pragma unroll
    for (int b = 0; b < 8; ++b) acc[a][b] = 0.f;

  int te = tid >> 4, tf = tid & 15;
  const float4* wg4 = (const float4*)sw;
  float4* ws4 = (float4*)ws;

  for (int k0 = 0; k0 < IN_F; k0 += 16) {
    __syncthreads();
    #pragma unroll
    for (int i = 0; i < 2; ++i) {
      int fi = i * 256 + tid;
      ws4[fi] = wg4[k0 * 32 + fi];
    }
    __syncthreads();
    #pragma unroll
    for (int kk = 0; kk < 16; ++kk) {
      float4 w0 = ws4[kk * 32 + tf];
      float4 w1 = ws4[kk * 32 + 16 + tf];
      #pragma unroll
      for (int rr = 0; rr < 4; ++rr) {
        float a = xs[(te * 4 + rr) * XS_STRIDE + k0 + kk];
        acc[rr][0] = fmaf(a, w0.x, acc[rr][0]);
        acc[rr][1] = fmaf(a, w0.y, acc[rr][1]);
        acc[rr][2] = fmaf(a, w0.z, acc[rr][2]);
        acc[rr][3] = fmaf(a, w0.w, acc[rr][3]);
        acc[rr][4] = fmaf(a, w1.x, acc[rr][4]);
        acc[rr][5] = fmaf(a, w1.y, acc[rr][5]);
        acc[rr][6] = fmaf(a, w1.z, acc[rr][6]);
        acc[rr][7] = fmaf(a, w1.w, acc[rr][7]);
      }
    }
  }

  float4 b0 = ((const float4*)bias)[tf];
  float4 b1 = ((const float4*)bias)[16 + tf];
  #pragma unroll
  for (int rr = 0; rr < 4; ++rr) {
    int row = te * 4 + rr;
    if (row < cnt) {
      int n = base + row;
      float4 o0 = make_float4(acc[rr][0] + b0.x, acc[rr][1] + b0.y,
                              acc[rr][2] + b0.z, acc[rr][3] + b0.w);
      float4 o1 = make_float4(acc[rr][4] + b1.x, acc[rr][5] + b1.y,
                              acc[rr][6] + b1.z, acc[rr][7] + b1.w);
      *(float4*)(out + (size_t)n * OUT_F + tf * 4) = o0;
      *(float4*)(out + (size_t)n * OUT_F + 64 + tf * 4) = o1;
    }
  }
}

// ------------- Kernel 9: per-node aggregation (one wave per node) -------------
__global__ __launch_bounds__(256) void k_agg(
    const ushort* __restrict__ msg, const int* __restrict__ csr,
    const int* __restrict__ row_off, float* __restrict__ out, int N) {
  int wv = (blockIdx.x * 256 + threadIdx.x) >> 6;
  int lane = threadIdx.x & 63;
  if (wv >= N) return;
  int lo = row_off[wv], hi = row_off[wv + 1];
  float a0 = 0.f, a1 = 0.f;
  for (int p = lo; p < hi; ++p) {
    int e = csr[p];
    uint v = *(const uint*)(msg + (size_t)e * OUT_F + lane * 2);
    a0 += __uint_as_float(v << 16);
    a1 += __uint_as_float(v & 0xFFFF0000u);
  }
  float inv = 1.f / (float)max(hi - lo, 1);
  float2* op = (float2*)(out + (size_t)wv * OUT_F + lane * 2);
  float2 o = *op;
  o.x += a0 * inv;
  o.y += a1 * inv;
  *op = o;
}

// ------------------------------- launch ---------------------------------------
extern "C" void kernel_launch(void* const* d_in, const int* in_sizes, int n_in,
                              void* d_out, int out_size, void* d_ws, size_t ws_size,
                              hipStream_t stream) {
  const float* x      = (const float*)d_in[0];
  const int*   ei     = (const int*)d_in[1];   // [2][E]
  const int*   etype  = (const int*)d_in[2];   // [E]
  const float* weight = (const float*)d_in[4]; // [B][128][128]
  const float* coeff  = (const float*)d_in[5]; // [R][B]
  const float* selfw  = (const float*)d_in[6]; // [128][128]
  const float* bias   = (const float*)d_in[7]; // [128]

  int N = in_sizes[0] / IN_F;
  int E = in_sizes[2];
  int B = in_sizes[4] / (IN_F * OUT_F);
  int R = in_sizes[5] / B;
  const int* src = ei;
  const int* tgt = ei + E;

  char* ws = (char*)d_ws;
  size_t off = 0;
  auto alloc = [&](size_t bytes) {
    char* p = ws + off;
    off += (bytes + 255) & ~(size_t)255;
    return p;
  };
  float*  relw    = (float*)alloc((size_t)R * IN_F * OUT_F * 4);
  int*    perm    = (int*)alloc((size_t)E * 4);
  int*    csr     = (int*)alloc((size_t)E * 4);
  int*    row_off = (int*)alloc((size_t)(N + 1) * 4);
  // zero region: ideg[N] | cursor_tgt[N] | hist[64] | cursor_rel[64]
  int*    ideg    = (int*)alloc((size_t)(2 * N + 128) * 4);
  int*    cur_t   = ideg + N;
  int*    hist    = cur_t + N;
  int*    cur_r   = hist + 64;
  int*    offs    = (int*)alloc(64 * 4);
  int*    toffs   = (int*)alloc(64 * 4);
  ushort* msg     = (ushort*)alloc((size_t)E * OUT_F * 2);

  hipMemsetAsync(ideg, 0, (size_t)(2 * N + 128) * 4, stream);

  k_relw<<<(R * IN_F * OUT_F + 255) / 256, 256, 0, stream>>>(weight, coeff, relw, R, B);
  k_hist_deg<<<(E + 255) / 256, 256, 0, stream>>>(etype, tgt, E, R, hist, ideg);
  k_scan<<<1, 64, 0, stream>>>(hist, offs, toffs, R);
  k_scatter<<<(E + 255) / 256, 256, 0, stream>>>(etype, E, R, offs, cur_r, perm);
  k_scan_nodes<<<1, 1024, 0, stream>>>(ideg, row_off, N);
  k_scatter_tgt<<<(E + 255) / 256, 256, 0, stream>>>(tgt, E, row_off, cur_t, csr);

  int maxTiles = (E + TILE_E - 1) / TILE_E + R;
  k_msg<<<maxTiles, 256, 0, stream>>>(x, src, perm, offs, toffs, relw, msg, R);
  k_self<<<(N + TILE_E - 1) / TILE_E, 256, 0, stream>>>(x, selfw, bias, (float*)d_out, N);
  k_agg<<<(N + 3) / 4, 256, 0, stream>>>(msg, csr, row_off, (float*)d_out, N);
}

// Round 3
// 465.983 us; speedup vs baseline: 6.6365x; 1.7740x over previous
//
#include <hip/hip_runtime.h>

#define IN_F 128
#define OUT_F 128
#define TILE_E 64
#define XS_STRIDE 132

typedef unsigned int uint;
typedef unsigned short ushort;
typedef __attribute__((ext_vector_type(8))) short bf16x8;
typedef __attribute__((ext_vector_type(4))) float f32x4;

__device__ inline ushort f2bf(float f) {
  uint u = __float_as_uint(f);
  uint r = (u + 0x7FFFu + ((u >> 16) & 1u)) >> 16;
  return (ushort)r;
}

// ---------------- Kernel 1: rel_w[r,i,o] = sum_b coeff[r,b] * weight[b,i,o] ----
__global__ void k_relw(const float* __restrict__ w, const float* __restrict__ c,
                       float* __restrict__ rw, int R, int B) {
  int idx = blockIdx.x * blockDim.x + threadIdx.x;
  if (idx >= R * IN_F * OUT_F) return;
  int r = idx >> 14;
  int io = idx & (IN_F * OUT_F - 1);
  float acc = 0.f;
  for (int b = 0; b < B; ++b) acc = fmaf(c[r * B + b], w[b * IN_F * OUT_F + io], acc);
  rw[idx] = acc;
}

// ---------------- Kernel 1b: transpose+convert rw[r][i][o] -> rwT[r][o][i] bf16
__global__ __launch_bounds__(256) void k_tr(const float* __restrict__ rw,
                                            ushort* __restrict__ rwT, int R) {
  __shared__ float t[64][65];
  int bid = blockIdx.x;            // R * 4
  int r = bid >> 2;
  int i0 = (bid & 1) * 64;
  int o0 = ((bid >> 1) & 1) * 64;
  int tid = threadIdx.x;
  const float4* s4 = (const float4*)(rw + (size_t)r * IN_F * OUT_F);
  #pragma unroll
  for (int it = 0; it < 4; ++it) {
    int idx = it * 256 + tid;      // 1024 float4 slots (64 rows x 16 chunks)
    int i = idx >> 4, c = idx & 15;
    float4 v = s4[(i0 + i) * 32 + (o0 >> 2) + c];
    t[i][c * 4 + 0] = v.x; t[i][c * 4 + 1] = v.y;
    t[i][c * 4 + 2] = v.z; t[i][c * 4 + 3] = v.w;
  }
  __syncthreads();
  ushort* dst = rwT + (size_t)r * IN_F * OUT_F;
  #pragma unroll
  for (int it = 0; it < 4; ++it) {
    int idx = it * 256 + tid;      // 1024 8B slots (64 o-rows x 16 chunks)
    int o = idx >> 4, c = idx & 15;
    uint2 pk;
    pk.x = (uint)f2bf(t[c * 4 + 0][o]) | ((uint)f2bf(t[c * 4 + 1][o]) << 16);
    pk.y = (uint)f2bf(t[c * 4 + 2][o]) | ((uint)f2bf(t[c * 4 + 3][o]) << 16);
    *(uint2*)(dst + (o0 + o) * IN_F + i0 + c * 4) = pk;
  }
}

// ---------------- Kernel 2: relation histogram + int in-degree ----------------
__global__ void k_hist_deg(const int* __restrict__ etype, const int* __restrict__ tgt,
                           int E, int R, int* __restrict__ hist, int* __restrict__ ideg) {
  __shared__ int lh[64];
  int tid = threadIdx.x;
  if (tid < R) lh[tid] = 0;
  __syncthreads();
  int e = blockIdx.x * blockDim.x + tid;
  if (e < E) {
    atomicAdd(&lh[etype[e]], 1);
    atomicAdd(&ideg[tgt[e]], 1);
  }
  __syncthreads();
  if (tid < R && lh[tid]) atomicAdd(&hist[tid], lh[tid]);
}

// ---------------- Kernel 3: tiny scan over R bins -----------------------------
__global__ void k_scan(const int* __restrict__ hist, int* __restrict__ offs,
                       int* __restrict__ toffs, int R) {
  if (threadIdx.x == 0) {
    int s = 0, t = 0;
    for (int r = 0; r < R; ++r) {
      offs[r] = s; toffs[r] = t;
      s += hist[r];
      t += (hist[r] + TILE_E - 1) / TILE_E;
    }
    offs[R] = s; toffs[R] = t;
  }
}

// ------- Kernel 4: counting-sort scatter of edge ids by relation (+inverse) ---
__global__ void k_scatter(const int* __restrict__ etype, int E, int R,
                          const int* __restrict__ offs, int* __restrict__ cursor,
                          int* __restrict__ perm, int* __restrict__ inv) {
  __shared__ int lh[64], lbase[64], lcur[64];
  int tid = threadIdx.x;
  if (tid < R) { lh[tid] = 0; lcur[tid] = 0; }
  __syncthreads();
  int e = blockIdx.x * blockDim.x + tid;
  int t = -1;
  if (e < E) { t = etype[e]; atomicAdd(&lh[t], 1); }
  __syncthreads();
  if (tid < R) lbase[tid] = lh[tid] ? atomicAdd(&cursor[tid], lh[tid]) : 0;
  __syncthreads();
  if (e < E) {
    int loc = atomicAdd(&lcur[t], 1);
    int slot = offs[t] + lbase[t] + loc;
    perm[slot] = e;
    inv[e] = slot;
  }
}

// ---------------- Kernel 5: exclusive scan of node degrees (single block) -----
__global__ __launch_bounds__(1024) void k_scan_nodes(
    const int* __restrict__ ideg, int* __restrict__ row_off, int N) {
  __shared__ int part[1024];
  int tid = threadIdx.x;
  int chunk = (N + 1023) >> 10;
  int lo = tid * chunk, hi = min(lo + chunk, N);
  int s = 0;
  for (int i = lo; i < hi; ++i) s += ideg[i];
  part[tid] = s;
  __syncthreads();
  for (int d = 1; d < 1024; d <<= 1) {
    int v = (tid >= d) ? part[tid - d] : 0;
    __syncthreads();
    part[tid] += v;
    __syncthreads();
  }
  int pre = (tid > 0) ? part[tid - 1] : 0;
  for (int i = lo; i < hi; ++i) { row_off[i] = pre; pre += ideg[i]; }
  if (tid == 1023) row_off[N] = part[1023];
}

// --------- Kernel 6: scatter edge SLOT ids (msg row index) into target-CSR ----
__global__ void k_scatter_tgt(const int* __restrict__ tgt, int E,
                              const int* __restrict__ row_off, const int* __restrict__ inv,
                              int* __restrict__ cursor, int* __restrict__ csr) {
  int e = blockIdx.x * blockDim.x + threadIdx.x;
  if (e < E) {
    int t = tgt[e];
    int pos = row_off[t] + atomicAdd(&cursor[t], 1);
    csr[pos] = inv[e];
  }
}

// ---------------- Kernel 7: per-relation-tile MFMA GEMM -> bf16 msg -----------
__global__ __launch_bounds__(256) void k_msg(
    const float* __restrict__ x, const int* __restrict__ src,
    const int* __restrict__ perm,
    const int* __restrict__ offs, const int* __restrict__ toffs,
    const ushort* __restrict__ rwT, ushort* __restrict__ msg, int R) {
  __shared__ ushort xs[TILE_E * IN_F];   // 16 KB bf16, XOR-swizzled rows
  __shared__ int ssrc[TILE_E];
  __shared__ int sinfo[2];
  int tid = threadIdx.x;
  int bid = blockIdx.x;
  if (tid == 0) {
    int r = -1;
    if (bid < toffs[R]) {
      r = 0;
      while (!(bid >= toffs[r] && bid < toffs[r + 1])) ++r;
    }
    sinfo[0] = r;
    sinfo[1] = (r >= 0) ? (offs[r] + (bid - toffs[r]) * TILE_E) : 0;
  }
  __syncthreads();
  int r = sinfo[0];
  if (r < 0) return;
  int ebase = sinfo[1];
  int cnt = min(TILE_E, offs[r + 1] - ebase);

  if (tid < TILE_E)
    ssrc[tid] = (tid < cnt) ? src[perm[ebase + tid]] : -1;
  __syncthreads();

  // stage x rows -> bf16 LDS, swizzle byte ^= (row&7)<<4 (16B-slot permute)
  const float4* x4 = (const float4*)x;
  char* xb = (char*)xs;
  #pragma unroll
  for (int i = 0; i < 8; ++i) {
    int idx = i * 256 + tid;       // 2048 float4 slots
    int e = idx >> 5;
    int c4 = idx & 31;
    float4 v = make_float4(0.f, 0.f, 0.f, 0.f);
    int s = ssrc[e];
    if (s >= 0) v = x4[(size_t)s * 32 + c4];
    uint2 pk;
    pk.x = (uint)f2bf(v.x) | ((uint)f2bf(v.y) << 16);
    pk.y = (uint)f2bf(v.z) | ((uint)f2bf(v.w) << 16);
    *(uint2*)(xb + e * 256 + ((c4 * 8) ^ ((e & 7) << 4))) = pk;
  }

  int wv = tid >> 6;           // wave 0..3 -> cols wv*32
  int l = tid & 63;
  int g = l >> 4;              // k-group
  int ln = l & 15;
  int wc = wv * 32;

  // B fragments from global (L2-resident): rwT[o][k], lane ln -> col, 8 contig k
  const ushort* wp = rwT + (size_t)r * IN_F * OUT_F;
  bf16x8 bfr[2][4];
  #pragma unroll
  for (int n = 0; n < 2; ++n)
    #pragma unroll
    for (int kk = 0; kk < 4; ++kk)
      bfr[n][kk] = *(const bf16x8*)(wp + (wc + n * 16 + ln) * IN_F + kk * 32 + g * 8);

  __syncthreads();

  f32x4 acc[4][2] = {};
  #pragma unroll
  for (int kk = 0; kk < 4; ++kk) {
    bf16x8 a[4];
    #pragma unroll
    for (int m = 0; m < 4; ++m) {
      int row = m * 16 + ln;
      int kb = kk * 64 + g * 16;
      a[m] = *(const bf16x8*)(xb + row * 256 + (kb ^ ((row & 7) << 4)));
    }
    #pragma unroll
    for (int m = 0; m < 4; ++m)
      #pragma unroll
      for (int n = 0; n < 2; ++n)
        acc[m][n] = __builtin_amdgcn_mfma_f32_16x16x32_bf16(a[m], bfr[n][kk],
                                                            acc[m][n], 0, 0, 0);
  }

  // epilogue: C/D col=lane&15, row=(lane>>4)*4+reg; msg row = tile slot (dense)
  #pragma unroll
  for (int m = 0; m < 4; ++m) {
    int rbase = m * 16 + g * 4;
    #pragma unroll
    for (int j = 0; j < 4; ++j) {
      int rr = rbase + j;
      if (rr < cnt) {
        ushort* mp = msg + (size_t)(ebase + rr) * OUT_F + wc + ln;
        mp[0]  = f2bf(acc[m][0][j]);
        mp[16] = f2bf(acc[m][1][j]);
      }
    }
  }
}

// ------------- Kernel 8: self-loop GEMM + bias (writes full out) --------------
__global__ __launch_bounds__(256) void k_self(
    const float* __restrict__ x, const float* __restrict__ sw,
    const float* __restrict__ bias, float* __restrict__ out, int N) {
  __shared__ float xsf[TILE_E * XS_STRIDE];
  __shared__ float wsf[16 * OUT_F];
  int tid = threadIdx.x;
  int base = blockIdx.x * TILE_E;
  int cnt = min(TILE_E, N - base);
  if (cnt <= 0) return;

  const float4* x4 = (const float4*)x;
  #pragma unroll
  for (int i = 0; i < 8; ++i) {
    int idx = i * 256 + tid;
    int e = idx >> 5;
    int c = idx & 31;
    int n = base + e;
    float4 v = make_float4(0.f, 0.f, 0.f, 0.f);
    if (n < N) v = x4[(size_t)n * 32 + c];
    *(float4*)(&xsf[e * XS_STRIDE + c * 4]) = v;
  }

  float acc[4][8];
  #pragma unroll
  for (int a = 0; a < 4; ++a)
    #pragma unroll
    for (int b = 0; b < 8; ++b) acc[a][b] = 0.f;

  int te = tid >> 4, tf = tid & 15;
  const float4* wg4 = (const float4*)sw;
  float4* ws4 = (float4*)wsf;

  for (int k0 = 0; k0 < IN_F; k0 += 16) {
    __syncthreads();
    #pragma unroll
    for (int i = 0; i < 2; ++i) {
      int fi = i * 256 + tid;
      ws4[fi] = wg4[k0 * 32 + fi];
    }
    __syncthreads();
    #pragma unroll
    for (int kk = 0; kk < 16; ++kk) {
      float4 w0 = ws4[kk * 32 + tf];
      float4 w1 = ws4[kk * 32 + 16 + tf];
      #pragma unroll
      for (int rr = 0; rr < 4; ++rr) {
        float a = xsf[(te * 4 + rr) * XS_STRIDE + k0 + kk];
        acc[rr][0] = fmaf(a, w0.x, acc[rr][0]);
        acc[rr][1] = fmaf(a, w0.y, acc[rr][1]);
        acc[rr][2] = fmaf(a, w0.z, acc[rr][2]);
        acc[rr][3] = fmaf(a, w0.w, acc[rr][3]);
        acc[rr][4] = fmaf(a, w1.x, acc[rr][4]);
        acc[rr][5] = fmaf(a, w1.y, acc[rr][5]);
        acc[rr][6] = fmaf(a, w1.z, acc[rr][6]);
        acc[rr][7] = fmaf(a, w1.w, acc[rr][7]);
      }
    }
  }

  float4 b0 = ((const float4*)bias)[tf];
  float4 b1 = ((const float4*)bias)[16 + tf];
  #pragma unroll
  for (int rr = 0; rr < 4; ++rr) {
    int row = te * 4 + rr;
    if (row < cnt) {
      int n = base + row;
      float4 o0 = make_float4(acc[rr][0] + b0.x, acc[rr][1] + b0.y,
                              acc[rr][2] + b0.z, acc[rr][3] + b0.w);
      float4 o1 = make_float4(acc[rr][4] + b1.x, acc[rr][5] + b1.y,
                              acc[rr][6] + b1.z, acc[rr][7] + b1.w);
      *(float4*)(out + (size_t)n * OUT_F + tf * 4) = o0;
      *(float4*)(out + (size_t)n * OUT_F + 64 + tf * 4) = o1;
    }
  }
}

// ------------- Kernel 9: per-node aggregation (one wave per node) -------------
__global__ __launch_bounds__(256) void k_agg(
    const ushort* __restrict__ msg, const int* __restrict__ csr,
    const int* __restrict__ row_off, float* __restrict__ out, int N) {
  int wv = (blockIdx.x * 256 + threadIdx.x) >> 6;
  int lane = threadIdx.x & 63;
  if (wv >= N) return;
  int lo = row_off[wv], hi = row_off[wv + 1];
  float a0 = 0.f, a1 = 0.f;
  int p = lo;
  for (; p + 4 <= hi; p += 4) {
    int e0 = csr[p], e1 = csr[p + 1], e2 = csr[p + 2], e3 = csr[p + 3];
    uint v0 = *(const uint*)(msg + (size_t)e0 * OUT_F + lane * 2);
    uint v1 = *(const uint*)(msg + (size_t)e1 * OUT_F + lane * 2);
    uint v2 = *(const uint*)(msg + (size_t)e2 * OUT_F + lane * 2);
    uint v3 = *(const uint*)(msg + (size_t)e3 * OUT_F + lane * 2);
    a0 += __uint_as_float(v0 << 16) + __uint_as_float(v1 << 16) +
          __uint_as_float(v2 << 16) + __uint_as_float(v3 << 16);
    a1 += __uint_as_float(v0 & 0xFFFF0000u) + __uint_as_float(v1 & 0xFFFF0000u) +
          __uint_as_float(v2 & 0xFFFF0000u) + __uint_as_float(v3 & 0xFFFF0000u);
  }
  for (; p < hi; ++p) {
    int e = csr[p];
    uint v = *(const uint*)(msg + (size_t)e * OUT_F + lane * 2);
    a0 += __uint_as_float(v << 16);
    a1 += __uint_as_float(v & 0xFFFF0000u);
  }
  float inv = 1.f / (float)max(hi - lo, 1);
  float2* op = (float2*)(out + (size_t)wv * OUT_F + lane * 2);
  float2 o = *op;
  o.x += a0 * inv;
  o.y += a1 * inv;
  *op = o;
}

// ------------------------------- launch ---------------------------------------
extern "C" void kernel_launch(void* const* d_in, const int* in_sizes, int n_in,
                              void* d_out, int out_size, void* d_ws, size_t ws_size,
                              hipStream_t stream) {
  const float* x      = (const float*)d_in[0];
  const int*   ei     = (const int*)d_in[1];   // [2][E]
  const int*   etype  = (const int*)d_in[2];   // [E]
  const float* weight = (const float*)d_in[4]; // [B][128][128]
  const float* coeff  = (const float*)d_in[5]; // [R][B]
  const float* selfw  = (const float*)d_in[6]; // [128][128]
  const float* bias   = (const float*)d_in[7]; // [128]

  int N = in_sizes[0] / IN_F;
  int E = in_sizes[2];
  int B = in_sizes[4] / (IN_F * OUT_F);
  int R = in_sizes[5] / B;
  const int* src = ei;
  const int* tgt = ei + E;

  char* ws = (char*)d_ws;
  size_t off = 0;
  auto alloc = [&](size_t bytes) {
    char* p = ws + off;
    off += (bytes + 255) & ~(size_t)255;
    return p;
  };
  float*  relw    = (float*)alloc((size_t)R * IN_F * OUT_F * 4);
  ushort* rwT     = (ushort*)alloc((size_t)R * IN_F * OUT_F * 2);
  int*    perm    = (int*)alloc((size_t)E * 4);
  int*    inv     = (int*)alloc((size_t)E * 4);
  int*    csr     = (int*)alloc((size_t)E * 4);
  int*    row_off = (int*)alloc((size_t)(N + 1) * 4);
  // zero region: ideg[N] | cursor_tgt[N] | hist[64] | cursor_rel[64]
  int*    ideg    = (int*)alloc((size_t)(2 * N + 128) * 4);
  int*    cur_t   = ideg + N;
  int*    hist    = cur_t + N;
  int*    cur_r   = hist + 64;
  int*    offs    = (int*)alloc(64 * 4);
  int*    toffs   = (int*)alloc(64 * 4);
  ushort* msg     = (ushort*)alloc((size_t)E * OUT_F * 2);

  hipMemsetAsync(ideg, 0, (size_t)(2 * N + 128) * 4, stream);

  k_relw<<<(R * IN_F * OUT_F + 255) / 256, 256, 0, stream>>>(weight, coeff, relw, R, B);
  k_tr<<<R * 4, 256, 0, stream>>>(relw, rwT, R);
  k_hist_deg<<<(E + 255) / 256, 256, 0, stream>>>(etype, tgt, E, R, hist, ideg);
  k_scan<<<1, 64, 0, stream>>>(hist, offs, toffs, R);
  k_scatter<<<(E + 255) / 256, 256, 0, stream>>>(etype, E, R, offs, cur_r, perm, inv);
  k_scan_nodes<<<1, 1024, 0, stream>>>(ideg, row_off, N);
  k_scatter_tgt<<<(E + 255) / 256, 256, 0, stream>>>(tgt, E, row_off, inv, cur_t, csr);

  int maxTiles = (E + TILE_E - 1) / TILE_E + R;
  k_msg<<<maxTiles, 256, 0, stream>>>(x, src, perm, offs, toffs, rwT, msg, R);
  k_self<<<(N + TILE_E - 1) / TILE_E, 256, 0, stream>>>(x, selfw, bias, (float*)d_out, N);
  k_agg<<<(N + 3) / 4, 256, 0, stream>>>(msg, csr, row_off, (float*)d_out, N);
}

// Round 4
// 381.885 us; speedup vs baseline: 8.0980x; 1.2202x over previous
//
#include <hip/hip_runtime.h>

#define IN_F 128
#define OUT_F 128
#define TILE_E 64

typedef unsigned int uint;
typedef unsigned short ushort;
typedef __attribute__((ext_vector_type(8))) short bf16x8;
typedef __attribute__((ext_vector_type(4))) float f32x4;

__device__ inline ushort f2bf(float f) {
  uint u = __float_as_uint(f);
  uint r = (u + 0x7FFFu + ((u >> 16) & 1u)) >> 16;
  return (ushort)r;
}

// ---------------- Kernel 1: rel_w[r,i,o] = sum_b coeff[r,b] * weight[b,i,o] ----
__global__ void k_relw(const float* __restrict__ w, const float* __restrict__ c,
                       float* __restrict__ rw, int R, int B) {
  int idx = blockIdx.x * blockDim.x + threadIdx.x;
  if (idx >= R * IN_F * OUT_F) return;
  int r = idx >> 14;
  int io = idx & (IN_F * OUT_F - 1);
  float acc = 0.f;
  for (int b = 0; b < B; ++b) acc = fmaf(c[r * B + b], w[b * IN_F * OUT_F + io], acc);
  rw[idx] = acc;
}

// ------- Kernel 1b: transpose+convert rw[r][i][o] -> rwT[r][o][i] bf16 --------
// r == R reads from selfw instead (self-loop weight gets slot R).
__global__ __launch_bounds__(256) void k_tr(const float* __restrict__ rw,
                                            const float* __restrict__ selfw,
                                            ushort* __restrict__ rwT, int R) {
  __shared__ float t[64][65];
  int bid = blockIdx.x;            // (R+1) * 4
  int r = bid >> 2;
  int i0 = (bid & 1) * 64;
  int o0 = ((bid >> 1) & 1) * 64;
  int tid = threadIdx.x;
  const float* srcp = (r < R) ? (rw + (size_t)r * IN_F * OUT_F) : selfw;
  const float4* s4 = (const float4*)srcp;
  #pragma unroll
  for (int it = 0; it < 4; ++it) {
    int idx = it * 256 + tid;      // 1024 float4 slots (64 rows x 16 chunks)
    int i = idx >> 4, c = idx & 15;
    float4 v = s4[(i0 + i) * 32 + (o0 >> 2) + c];
    t[i][c * 4 + 0] = v.x; t[i][c * 4 + 1] = v.y;
    t[i][c * 4 + 2] = v.z; t[i][c * 4 + 3] = v.w;
  }
  __syncthreads();
  ushort* dst = rwT + (size_t)r * IN_F * OUT_F;
  #pragma unroll
  for (int it = 0; it < 4; ++it) {
    int idx = it * 256 + tid;      // 1024 8B slots (64 o-rows x 16 chunks)
    int o = idx >> 4, c = idx & 15;
    uint2 pk;
    pk.x = (uint)f2bf(t[c * 4 + 0][o]) | ((uint)f2bf(t[c * 4 + 1][o]) << 16);
    pk.y = (uint)f2bf(t[c * 4 + 2][o]) | ((uint)f2bf(t[c * 4 + 3][o]) << 16);
    *(uint2*)(dst + (o0 + o) * IN_F + i0 + c * 4) = pk;
  }
}

// ---------------- Kernel 1c: x fp32 -> bf16 -----------------------------------
__global__ void k_xbf(const float* __restrict__ x, ushort* __restrict__ xbf, int n4) {
  int i = blockIdx.x * blockDim.x + threadIdx.x;
  if (i >= n4) return;
  float4 v = ((const float4*)x)[i];
  uint2 pk;
  pk.x = (uint)f2bf(v.x) | ((uint)f2bf(v.y) << 16);
  pk.y = (uint)f2bf(v.z) | ((uint)f2bf(v.w) << 16);
  ((uint2*)xbf)[i] = pk;
}

// ---------------- Kernel 2: relation histogram + int in-degree ----------------
__global__ void k_hist_deg(const int* __restrict__ etype, const int* __restrict__ tgt,
                           int E, int R, int* __restrict__ hist, int* __restrict__ ideg) {
  __shared__ int lh[64];
  int tid = threadIdx.x;
  if (tid < R) lh[tid] = 0;
  __syncthreads();
  int e = blockIdx.x * blockDim.x + tid;
  if (e < E) {
    atomicAdd(&lh[etype[e]], 1);
    atomicAdd(&ideg[tgt[e]], 1);
  }
  __syncthreads();
  if (tid < R && lh[tid]) atomicAdd(&hist[tid], lh[tid]);
}

// ---------------- Kernel 3: tiny scan over R bins -----------------------------
__global__ void k_scan(const int* __restrict__ hist, int* __restrict__ offs,
                       int* __restrict__ toffs, int R) {
  if (threadIdx.x == 0) {
    int s = 0, t = 0;
    for (int r = 0; r < R; ++r) {
      offs[r] = s; toffs[r] = t;
      s += hist[r];
      t += (hist[r] + TILE_E - 1) / TILE_E;
    }
    offs[R] = s; toffs[R] = t;
  }
}

// ---------------- Kernel 5: exclusive scan of node degrees (single block) -----
__global__ __launch_bounds__(1024) void k_scan_nodes(
    const int* __restrict__ ideg, int* __restrict__ row_off, int N) {
  __shared__ int part[1024];
  int tid = threadIdx.x;
  int chunk = (N + 1023) >> 10;
  int lo = tid * chunk, hi = min(lo + chunk, N);
  int s = 0;
  for (int i = lo; i < hi; ++i) s += ideg[i];
  part[tid] = s;
  __syncthreads();
  for (int d = 1; d < 1024; d <<= 1) {
    int v = (tid >= d) ? part[tid - d] : 0;
    __syncthreads();
    part[tid] += v;
    __syncthreads();
  }
  int pre = (tid > 0) ? part[tid - 1] : 0;
  for (int i = lo; i < hi; ++i) { row_off[i] = pre; pre += ideg[i]; }
  if (tid == 1023) row_off[N] = part[1023];
}

// ------- Kernel 6: fused counting-sort: perm[slot]=src node, wpos[slot]=csr pos
__global__ void k_scatter2(const int* __restrict__ etype, const int* __restrict__ src,
                           const int* __restrict__ tgt, int E, int R,
                           const int* __restrict__ offs, const int* __restrict__ row_off,
                           int* __restrict__ cur_r, int* __restrict__ cur_t,
                           int* __restrict__ perm, int* __restrict__ wpos) {
  __shared__ int lh[64], lbase[64], lcur[64];
  int tid = threadIdx.x;
  if (tid < R) { lh[tid] = 0; lcur[tid] = 0; }
  __syncthreads();
  int e = blockIdx.x * blockDim.x + tid;
  int t = -1;
  if (e < E) { t = etype[e]; atomicAdd(&lh[t], 1); }
  __syncthreads();
  if (tid < R) lbase[tid] = lh[tid] ? atomicAdd(&cur_r[tid], lh[tid]) : 0;
  __syncthreads();
  if (e < E) {
    int loc = atomicAdd(&lcur[t], 1);
    int slot = offs[t] + lbase[t] + loc;
    perm[slot] = src[e];
    int tg = tgt[e];
    int pos = row_off[tg] + atomicAdd(&cur_t[tg], 1);
    wpos[slot] = pos;
  }
}

// ---------------- Kernel 7: per-relation-tile MFMA GEMM -> msg[csr order] -----
__global__ __launch_bounds__(256) void k_msg(
    const ushort* __restrict__ xbf, const int* __restrict__ perm,
    const int* __restrict__ wpos,
    const int* __restrict__ offs, const int* __restrict__ toffs,
    const ushort* __restrict__ rwT, ushort* __restrict__ msg, int R) {
  __shared__ ushort xs[TILE_E * IN_F];   // 16 KB bf16, XOR-swizzled rows
  __shared__ int ssrc[TILE_E];
  __shared__ int swp[TILE_E];
  __shared__ int sinfo[2];
  int tid = threadIdx.x;
  int bid = blockIdx.x;
  if (tid == 0) {
    int r = -1;
    if (bid < toffs[R]) {
      r = 0;
      while (!(bid >= toffs[r] && bid < toffs[r + 1])) ++r;
    }
    sinfo[0] = r;
    sinfo[1] = (r >= 0) ? (offs[r] + (bid - toffs[r]) * TILE_E) : 0;
  }
  __syncthreads();
  int r = sinfo[0];
  if (r < 0) return;
  int ebase = sinfo[1];
  int cnt = min(TILE_E, offs[r + 1] - ebase);

  if (tid < TILE_E) {
    int ok = tid < cnt;
    ssrc[tid] = ok ? perm[ebase + tid] : -1;
    swp[tid] = ok ? wpos[ebase + tid] : 0;
  }
  __syncthreads();

  // stage bf16 x rows -> LDS, 16B chunks, swizzle byte ^= (row&7)<<4
  char* xb = (char*)xs;
  #pragma unroll
  for (int i = 0; i < 4; ++i) {
    int idx = i * 256 + tid;       // 1024 16B chunks
    int row = idx >> 4, c = idx & 15;
    bf16x8 v = {};
    int s = ssrc[row];
    if (s >= 0) v = *(const bf16x8*)(xbf + (size_t)s * IN_F + c * 8);
    *(bf16x8*)(xb + row * 256 + ((c * 16) ^ ((row & 7) << 4))) = v;
  }

  int wv = tid >> 6;           // wave 0..3 -> cols wv*32
  int l = tid & 63;
  int g = l >> 4;              // k-group
  int ln = l & 15;
  int wc = wv * 32;

  // B fragments from global (L2-resident): rwT[o][k]
  const ushort* wp = rwT + (size_t)r * IN_F * OUT_F;
  bf16x8 bfr[2][4];
  #pragma unroll
  for (int n = 0; n < 2; ++n)
    #pragma unroll
    for (int kk = 0; kk < 4; ++kk)
      bfr[n][kk] = *(const bf16x8*)(wp + (wc + n * 16 + ln) * IN_F + kk * 32 + g * 8);

  __syncthreads();

  f32x4 acc[4][2] = {};
  #pragma unroll
  for (int kk = 0; kk < 4; ++kk) {
    bf16x8 a[4];
    #pragma unroll
    for (int m = 0; m < 4; ++m) {
      int row = m * 16 + ln;
      int kb = kk * 64 + g * 16;
      a[m] = *(const bf16x8*)(xb + row * 256 + (kb ^ ((row & 7) << 4)));
    }
    #pragma unroll
    for (int m = 0; m < 4; ++m)
      #pragma unroll
      for (int n = 0; n < 2; ++n)
        acc[m][n] = __builtin_amdgcn_mfma_f32_16x16x32_bf16(a[m], bfr[n][kk],
                                                            acc[m][n], 0, 0, 0);
  }

  // epilogue: C/D col=lane&15, row=(lane>>4)*4+reg; write to csr-ordered slot
  #pragma unroll
  for (int m = 0; m < 4; ++m) {
    int rbase = m * 16 + g * 4;
    #pragma unroll
    for (int j = 0; j < 4; ++j) {
      int rr = rbase + j;
      if (rr < cnt) {
        ushort* mp = msg + (size_t)swp[rr] * OUT_F + wc + ln;
        mp[0]  = f2bf(acc[m][0][j]);
        mp[16] = f2bf(acc[m][1][j]);
      }
    }
  }
}

// ------------- Kernel 8: self-loop MFMA GEMM + bias (writes full out) ---------
__global__ __launch_bounds__(256) void k_self(
    const ushort* __restrict__ xbf, const ushort* __restrict__ swT,
    const float* __restrict__ bias, float* __restrict__ out, int N) {
  __shared__ ushort xs[TILE_E * IN_F];
  int tid = threadIdx.x;
  int base = blockIdx.x * TILE_E;

  char* xb = (char*)xs;
  #pragma unroll
  for (int i = 0; i < 4; ++i) {
    int idx = i * 256 + tid;
    int row = idx >> 4, c = idx & 15;
    int n = base + row;
    bf16x8 v = {};
    if (n < N) v = *(const bf16x8*)(xbf + (size_t)n * IN_F + c * 8);
    *(bf16x8*)(xb + row * 256 + ((c * 16) ^ ((row & 7) << 4))) = v;
  }

  int wv = tid >> 6;
  int l = tid & 63;
  int g = l >> 4;
  int ln = l & 15;
  int wc = wv * 32;

  bf16x8 bfr[2][4];
  #pragma unroll
  for (int n = 0; n < 2; ++n)
    #pragma unroll
    for (int kk = 0; kk < 4; ++kk)
      bfr[n][kk] = *(const bf16x8*)(swT + (wc + n * 16 + ln) * IN_F + kk * 32 + g * 8);

  __syncthreads();

  f32x4 acc[4][2] = {};
  #pragma unroll
  for (int kk = 0; kk < 4; ++kk) {
    bf16x8 a[4];
    #pragma unroll
    for (int m = 0; m < 4; ++m) {
      int row = m * 16 + ln;
      int kb = kk * 64 + g * 16;
      a[m] = *(const bf16x8*)(xb + row * 256 + (kb ^ ((row & 7) << 4)));
    }
    #pragma unroll
    for (int m = 0; m < 4; ++m)
      #pragma unroll
      for (int n = 0; n < 2; ++n)
        acc[m][n] = __builtin_amdgcn_mfma_f32_16x16x32_bf16(a[m], bfr[n][kk],
                                                            acc[m][n], 0, 0, 0);
  }

  float b0 = bias[wc + ln];
  float b1 = bias[wc + 16 + ln];
  #pragma unroll
  for (int m = 0; m < 4; ++m) {
    int rbase = m * 16 + g * 4;
    #pragma unroll
    for (int j = 0; j < 4; ++j) {
      int n = base + rbase + j;
      if (n < N) {
        out[(size_t)n * OUT_F + wc + ln]      = acc[m][0][j] + b0;
        out[(size_t)n * OUT_F + wc + 16 + ln] = acc[m][1][j] + b1;
      }
    }
  }
}

// ------------- Kernel 9: per-node aggregation (contiguous msg rows) -----------
__global__ __launch_bounds__(256) void k_agg(
    const ushort* __restrict__ msg, const int* __restrict__ row_off,
    float* __restrict__ out, int N) {
  int wv = (blockIdx.x * 256 + threadIdx.x) >> 6;
  int lane = threadIdx.x & 63;
  if (wv >= N) return;
  int lo = row_off[wv], hi = row_off[wv + 1];
  const uint* mp = (const uint*)msg + (size_t)lo * 64 + lane;
  float a0 = 0.f, a1 = 0.f;
  int p = lo;
  for (; p + 4 <= hi; p += 4, mp += 256) {
    uint v0 = mp[0], v1 = mp[64], v2 = mp[128], v3 = mp[192];
    a0 += __uint_as_float(v0 << 16) + __uint_as_float(v1 << 16) +
          __uint_as_float(v2 << 16) + __uint_as_float(v3 << 16);
    a1 += __uint_as_float(v0 & 0xFFFF0000u) + __uint_as_float(v1 & 0xFFFF0000u) +
          __uint_as_float(v2 & 0xFFFF0000u) + __uint_as_float(v3 & 0xFFFF0000u);
  }
  for (; p < hi; ++p, mp += 64) {
    uint v = *mp;
    a0 += __uint_as_float(v << 16);
    a1 += __uint_as_float(v & 0xFFFF0000u);
  }
  float inv = 1.f / (float)max(hi - lo, 1);
  float2* op = (float2*)(out + (size_t)wv * OUT_F + lane * 2);
  float2 o = *op;
  o.x += a0 * inv;
  o.y += a1 * inv;
  *op = o;
}

// ------------------------------- launch ---------------------------------------
extern "C" void kernel_launch(void* const* d_in, const int* in_sizes, int n_in,
                              void* d_out, int out_size, void* d_ws, size_t ws_size,
                              hipStream_t stream) {
  const float* x      = (const float*)d_in[0];
  const int*   ei     = (const int*)d_in[1];   // [2][E]
  const int*   etype  = (const int*)d_in[2];   // [E]
  const float* weight = (const float*)d_in[4]; // [B][128][128]
  const float* coeff  = (const float*)d_in[5]; // [R][B]
  const float* selfw  = (const float*)d_in[6]; // [128][128]
  const float* bias   = (const float*)d_in[7]; // [128]

  int N = in_sizes[0] / IN_F;
  int E = in_sizes[2];
  int B = in_sizes[4] / (IN_F * OUT_F);
  int R = in_sizes[5] / B;
  const int* src = ei;
  const int* tgt = ei + E;

  char* ws = (char*)d_ws;
  size_t off = 0;
  auto alloc = [&](size_t bytes) {
    char* p = ws + off;
    off += (bytes + 255) & ~(size_t)255;
    return p;
  };
  float*  relw    = (float*)alloc((size_t)R * IN_F * OUT_F * 4);
  ushort* rwT     = (ushort*)alloc((size_t)(R + 1) * IN_F * OUT_F * 2);
  ushort* xbf     = (ushort*)alloc((size_t)N * IN_F * 2);
  int*    perm    = (int*)alloc((size_t)E * 4);
  int*    wpos    = (int*)alloc((size_t)E * 4);
  int*    row_off = (int*)alloc((size_t)(N + 1) * 4);
  // zero region: ideg[N] | cursor_tgt[N] | hist[64] | cursor_rel[64]
  int*    ideg    = (int*)alloc((size_t)(2 * N + 128) * 4);
  int*    cur_t   = ideg + N;
  int*    hist    = cur_t + N;
  int*    cur_r   = hist + 64;
  int*    offs    = (int*)alloc(64 * 4);
  int*    toffs   = (int*)alloc(64 * 4);
  ushort* msg     = (ushort*)alloc((size_t)E * OUT_F * 2);

  hipMemsetAsync(ideg, 0, (size_t)(2 * N + 128) * 4, stream);

  k_relw<<<(R * IN_F * OUT_F + 255) / 256, 256, 0, stream>>>(weight, coeff, relw, R, B);
  k_tr<<<(R + 1) * 4, 256, 0, stream>>>(relw, selfw, rwT, R);
  k_xbf<<<(N * IN_F / 4 + 255) / 256, 256, 0, stream>>>(x, xbf, N * IN_F / 4);
  k_hist_deg<<<(E + 255) / 256, 256, 0, stream>>>(etype, tgt, E, R, hist, ideg);
  k_scan<<<1, 64, 0, stream>>>(hist, offs, toffs, R);
  k_scan_nodes<<<1, 1024, 0, stream>>>(ideg, row_off, N);
  k_scatter2<<<(E + 255) / 256, 256, 0, stream>>>(etype, src, tgt, E, R, offs, row_off,
                                                  cur_r, cur_t, perm, wpos);

  int maxTiles = (E + TILE_E - 1) / TILE_E + R;
  k_msg<<<maxTiles, 256, 0, stream>>>(xbf, perm, wpos, offs, toffs, rwT, msg, R);
  k_self<<<(N + TILE_E - 1) / TILE_E, 256, 0, stream>>>(
      xbf, rwT + (size_t)R * IN_F * OUT_F, bias, (float*)d_out, N);
  k_agg<<<(N + 3) / 4, 256, 0, stream>>>(msg, row_off, (float*)d_out, N);
}